// Round 3
// baseline (1021.882 us; speedup 1.0000x reference)
//
#include <hip/hip_runtime.h>

#define C_ 128
#define N0 16384
#define E0 65024
#define NC_ 1024
#define E1C 3968

__device__ __forceinline__ int cprefix(int ci, int cj) {
  // sum of out-degrees of coarse clusters before (ci,cj) in row-major order (32x32 grid)
  int rows = (ci == 0) ? 0 : (94 + (ci - 1) * 126);
  int v = (ci > 0) + (ci < 31);
  int within = (cj == 0) ? 0 : (2 * cj - 1);
  return rows + within + cj * v;
}

__device__ __forceinline__ void add4(float4& s, const float* p) {
  float4 v = *(const float4*)p;
  s.x += v.x; s.y += v.y; s.z += v.z; s.w += v.w;
}

// MODE 0: edge MLP, K1=384, A = [e_row | x[src] | x[dst]]
// MODE 1: node MLP, K1=256, A = [x_row | agg_row]
// out = io + relu(A@W1 + b1)@W2 + b2, written in place to io.
template<int MODE>
__global__ __launch_bounds__(256, 3) void mlp_kernel(
    float* __restrict__ io,
    const float* __restrict__ xin,
    const int* __restrict__ srcI, const int* __restrict__ dstI,
    const float* __restrict__ W1, const float* __restrict__ b1,
    const float* __restrict__ W2, const float* __restrict__ b2)
{
  __shared__ float sA[32][68];     // k-major A tile (pad 68 vs 64)
  __shared__ float sW[32][128];
  __shared__ int sS[64], sD[64];

  const int tid = threadIdx.x;
  const int r0 = blockIdx.x * 64;
  const int ty = tid >> 4, tx = tid & 15;

  if (MODE == 0) {
    if (tid < 64) sS[tid] = srcI[r0 + tid];
    else if (tid < 128) sD[tid - 64] = dstI[r0 + tid - 64];
  }
  __syncthreads();

  float acc[4][8];
  #pragma unroll
  for (int i = 0; i < 4; ++i)
    #pragma unroll
    for (int j = 0; j < 8; ++j) acc[i][j] = 0.f;

  const int NKT = (MODE == 0) ? 12 : 8;
  for (int kt = 0; kt < NKT; ++kt) {
    const int region = kt >> 2;
    const int colbase = (kt & 3) * 32;
    // stage A tile (64 rows x 32 k) transposed into sA[kk][row]
    #pragma unroll
    for (int t = 0; t < 2; ++t) {
      int s = tid * 2 + t;            // 0..511 float4 slots
      int row = s >> 3;               // 0..63
      int q = s & 7;                  // 0..7
      const float* rp;
      if (MODE == 0) {
        if (region == 0)      rp = io  + (r0 + row) * C_;
        else if (region == 1) rp = xin + sS[row] * C_;
        else                  rp = xin + sD[row] * C_;
      } else {
        if (region == 0)      rp = io  + (r0 + row) * C_;
        else                  rp = xin + (r0 + row) * C_;
      }
      float4 a = *(const float4*)(rp + colbase + q * 4);
      sA[q*4+0][row] = a.x; sA[q*4+1][row] = a.y;
      sA[q*4+2][row] = a.z; sA[q*4+3][row] = a.w;
    }
    // stage W1 tile rows kt*32..+31 (contiguous)
    #pragma unroll
    for (int t = 0; t < 4; ++t) {
      int s = tid + t * 256;
      int kk = s >> 5, q = s & 31;
      *(float4*)&sW[kk][q*4] = *(const float4*)(W1 + (kt*32 + kk) * C_ + q*4);
    }
    __syncthreads();
    #pragma unroll
    for (int kk = 0; kk < 32; ++kk) {
      float4 av = *(const float4*)&sA[kk][ty*4];
      float4 w0 = *(const float4*)&sW[kk][tx*4];
      float4 w1 = *(const float4*)&sW[kk][64 + tx*4];
      float a_[4] = {av.x, av.y, av.z, av.w};
      float w_[8] = {w0.x, w0.y, w0.z, w0.w, w1.x, w1.y, w1.z, w1.w};
      #pragma unroll
      for (int i = 0; i < 4; ++i)
        #pragma unroll
        for (int j = 0; j < 8; ++j)
          acc[i][j] = fmaf(a_[i], w_[j], acc[i][j]);
    }
    __syncthreads();
  }

  // bias + relu (acc becomes H); thread owns cols {tx*4..+3} and {64+tx*4..+3}
  #pragma unroll
  for (int j = 0; j < 8; ++j) {
    int col = (j < 4) ? (tx*4 + j) : (64 + tx*4 + (j - 4));
    float bb = b1[col];
    #pragma unroll
    for (int i = 0; i < 4; ++i)
      acc[i][j] = fmaxf(acc[i][j] + bb, 0.f);
  }

  float acc2[4][8];
  #pragma unroll
  for (int i = 0; i < 4; ++i)
    #pragma unroll
    for (int j = 0; j < 8; ++j) acc2[i][j] = 0.f;

  // GEMM2: H(64x128) @ W2(128x128) in 4 k-chunks of 32, reusing sA/sW
  for (int kc = 0; kc < 4; ++kc) {
    int txlo = (kc & 1) * 8;
    int jbase = (kc >> 1) * 4;
    if (tx >= txlo && tx < txlo + 8) {
      #pragma unroll
      for (int jj = 0; jj < 4; ++jj) {
        int kk = (tx - txlo) * 4 + jj;
        #pragma unroll
        for (int i = 0; i < 4; ++i)
          sA[kk][ty*4 + i] = acc[i][jbase + jj];
      }
    }
    #pragma unroll
    for (int t = 0; t < 4; ++t) {
      int s = tid + t * 256;
      int kk = s >> 5, q = s & 31;
      *(float4*)&sW[kk][q*4] = *(const float4*)(W2 + (kc*32 + kk) * C_ + q*4);
    }
    __syncthreads();
    #pragma unroll
    for (int kk = 0; kk < 32; ++kk) {
      float4 av = *(const float4*)&sA[kk][ty*4];
      float4 w0 = *(const float4*)&sW[kk][tx*4];
      float4 w1 = *(const float4*)&sW[kk][64 + tx*4];
      float a_[4] = {av.x, av.y, av.z, av.w};
      float w_[8] = {w0.x, w0.y, w0.z, w0.w, w1.x, w1.y, w1.z, w1.w};
      #pragma unroll
      for (int i = 0; i < 4; ++i)
        #pragma unroll
        for (int j = 0; j < 8; ++j)
          acc2[i][j] = fmaf(a_[i], w_[j], acc2[i][j]);
    }
    __syncthreads();
  }

  // epilogue: io += acc2 + b2
  #pragma unroll
  for (int i = 0; i < 4; ++i) {
    int row = r0 + ty*4 + i;
    float* op = io + row * C_;
    #pragma unroll
    for (int half = 0; half < 2; ++half) {
      int col = half * 64 + tx * 4;
      float4 old = *(const float4*)(op + col);
      int jb = half * 4;
      float4 o;
      o.x = old.x + acc2[i][jb+0] + b2[col+0];
      o.y = old.y + acc2[i][jb+1] + b2[col+1];
      o.z = old.z + acc2[i][jb+2] + b2[col+2];
      o.w = old.w + acc2[i][jb+3] + b2[col+3];
      *(float4*)(op + col) = o;
    }
  }
}

// agg[n] = sum of e over in-edges of fine node n (fixed 128x128 grid structure)
__global__ void agg_fine(const float* __restrict__ e, float* __restrict__ agg) {
  int idx = blockIdx.x * 256 + threadIdx.x;   // 16384*32
  int n = idx >> 5;
  int c4 = (idx & 31) * 4;
  int i = n >> 7, j = n & 127;
  float4 s = make_float4(0.f, 0.f, 0.f, 0.f);
  if (j >= 1)   add4(s, e + (i*127 + (j-1)) * C_ + c4);            // from left  (block0)
  if (j <= 126) add4(s, e + (16256 + i*127 + j) * C_ + c4);        // from right (block1)
  if (i >= 1)   add4(s, e + (32512 + (i-1)*128 + j) * C_ + c4);    // from up    (block2)
  if (i <= 126) add4(s, e + (48768 + i*128 + j) * C_ + c4);        // from down  (block3)
  *(float4*)(agg + n * C_ + c4) = s;
}

__global__ void agg_coarse(const float* __restrict__ e1, float* __restrict__ agg1) {
  int idx = blockIdx.x * 256 + threadIdx.x;   // 1024*32
  int m = idx >> 5;
  int c4 = (idx & 31) * 4;
  int ci = m >> 5, cj = m & 31;
  float4 s = make_float4(0.f, 0.f, 0.f, 0.f);
  if (ci > 0)  add4(s, e1 + (cprefix(ci-1,cj) + (ci-1>0) + (cj>0) + (cj<31)) * C_ + c4);
  if (cj > 0)  add4(s, e1 + (cprefix(ci,cj-1) + (ci>0) + (cj-1>0)) * C_ + c4);
  if (cj < 31) add4(s, e1 + (cprefix(ci,cj+1) + (ci>0)) * C_ + c4);
  if (ci < 31) add4(s, e1 + (cprefix(ci+1,cj)) * C_ + c4);
  *(float4*)(agg1 + m * C_ + c4) = s;
}

__global__ void pool_x(const float* __restrict__ x, float* __restrict__ x1) {
  int idx = blockIdx.x * 256 + threadIdx.x;   // 1024*32
  int m = idx >> 5;
  int c4 = (idx & 31) * 4;
  int ci = m >> 5, cj = m & 31;
  float4 s = make_float4(0.f, 0.f, 0.f, 0.f);
  #pragma unroll
  for (int a = 0; a < 4; ++a)
    #pragma unroll
    for (int b = 0; b < 4; ++b)
      add4(s, x + ((4*ci + a) * 128 + 4*cj + b) * C_ + c4);
  s.x *= 0.0625f; s.y *= 0.0625f; s.z *= 0.0625f; s.w *= 0.0625f;
  *(float4*)(x1 + m * C_ + c4) = s;
}

// e1[coarse_edge] = sum of the 4 fine boundary-crossing edges
__global__ void pool_e(const float* __restrict__ e, float* __restrict__ e1) {
  int idx = blockIdx.x * 256 + threadIdx.x;   // 4096*32 (1024 clusters x 4 dirs)
  int combo = idx >> 5;
  int c4 = (idx & 31) * 4;
  int m = combo >> 2, dir = combo & 3;
  int ci = m >> 5, cj = m & 31;
  int cid, f0, fstep;
  if (dir == 0) { if (ci == 0) return;                       // up-out
    cid = cprefix(ci,cj);
    f0 = 48768 + (4*ci - 1) * 128 + 4*cj; fstep = 1;
  } else if (dir == 1) { if (cj == 0) return;                // left-out
    cid = cprefix(ci,cj) + (ci>0);
    f0 = 16256 + (4*ci) * 127 + 4*cj - 1; fstep = 127;
  } else if (dir == 2) { if (cj == 31) return;               // right-out
    cid = cprefix(ci,cj) + (ci>0) + (cj>0);
    f0 = (4*ci) * 127 + 4*cj + 3; fstep = 127;
  } else { if (ci == 31) return;                             // down-out
    cid = cprefix(ci,cj) + (ci>0) + (cj>0) + (cj<31);
    f0 = 32512 + (4*ci + 3) * 128 + 4*cj; fstep = 1;
  }
  float4 s = make_float4(0.f, 0.f, 0.f, 0.f);
  #pragma unroll
  for (int k = 0; k < 4; ++k)
    add4(s, e + (f0 + k * fstep) * C_ + c4);
  *(float4*)(e1 + cid * C_ + c4) = s;
}

__global__ void unpool_x(float* __restrict__ x, const float* __restrict__ x1,
                         const int* __restrict__ perm) {
  int idx = blockIdx.x * 256 + threadIdx.x;   // 16384*32
  int n = idx >> 5, c4 = (idx & 31) * 4;
  int m = perm[n];
  float4 v = *(const float4*)(x + n * C_ + c4);
  add4(v, x1 + m * C_ + c4);
  *(float4*)(x + n * C_ + c4) = v;
}

__global__ void unpool_e(float* __restrict__ e, const float* __restrict__ e1,
                         const int* __restrict__ pe) {
  int idx = blockIdx.x * 256 + threadIdx.x;   // 3968*32
  int k = idx >> 5, c4 = (idx & 31) * 4;
  int fe = pe[k];
  float4 v = *(const float4*)(e + fe * C_ + c4);
  add4(v, e1 + k * C_ + c4);
  *(float4*)(e + fe * C_ + c4) = v;
}

extern "C" void kernel_launch(void* const* d_in, const int* in_sizes, int n_in,
                              void* d_out, int out_size, void* d_ws, size_t ws_size,
                              hipStream_t stream) {
  const float* in_x  = (const float*)d_in[0];
  const float* in_ea = (const float*)d_in[1];
  const float* We1 = (const float*)d_in[2];
  const float* be1 = (const float*)d_in[3];
  const float* We2 = (const float*)d_in[4];
  const float* be2 = (const float*)d_in[5];
  const float* Wn1 = (const float*)d_in[6];
  const float* bn1 = (const float*)d_in[7];
  const float* Wn2 = (const float*)d_in[8];
  const float* bn2 = (const float*)d_in[9];
  const int* ei   = (const int*)d_in[10];
  const int* perm = (const int*)d_in[11];
  const int* pei  = (const int*)d_in[12];
  const int* pe   = (const int*)d_in[14];

  // x and e live directly in d_out (they ARE the outputs, concatenated).
  float* x = (float*)d_out;             // N0 x 128
  float* e = x + (size_t)N0 * C_;       // E0 x 128
  // small scratch in d_ws (~11.5 MB total)
  float* agg  = (float*)d_ws;           // N0 x 128
  float* x1   = agg + (size_t)N0 * C_;  // NC x 128
  float* e1   = x1 + (size_t)NC_ * C_;  // E1 x 128
  float* agg1 = e1 + (size_t)E1C * C_;  // NC x 128

  hipMemcpyAsync(x, in_x, (size_t)N0 * C_ * 4, hipMemcpyDeviceToDevice, stream);
  hipMemcpyAsync(e, in_ea, (size_t)E0 * C_ * 4, hipMemcpyDeviceToDevice, stream);

  const int* srcF = ei;  const int* dstF = ei + E0;
  const int* srcC = pei; const int* dstC = pei + E1C;

  for (int l = 0; l < 2; ++l) {
    mlp_kernel<0><<<E0/64, 256, 0, stream>>>(e, x, srcF, dstF,
        We1 + l*384*C_, be1 + l*C_, We2 + l*C_*C_, be2 + l*C_);
    agg_fine<<<N0*32/256, 256, 0, stream>>>(e, agg);
    mlp_kernel<1><<<N0/64, 256, 0, stream>>>(x, agg, nullptr, nullptr,
        Wn1 + l*256*C_, bn1 + l*C_, Wn2 + l*C_*C_, bn2 + l*C_);
  }

  pool_x<<<NC_*32/256, 256, 0, stream>>>(x, x1);
  pool_e<<<NC_*4*32/256, 256, 0, stream>>>(e, e1);

  for (int l = 2; l < 4; ++l) {
    mlp_kernel<0><<<E1C/64, 256, 0, stream>>>(e1, x1, srcC, dstC,
        We1 + l*384*C_, be1 + l*C_, We2 + l*C_*C_, be2 + l*C_);
    agg_coarse<<<NC_*32/256, 256, 0, stream>>>(e1, agg1);
    mlp_kernel<1><<<NC_/64, 256, 0, stream>>>(x1, agg1, nullptr, nullptr,
        Wn1 + l*256*C_, bn1 + l*C_, Wn2 + l*C_*C_, bn2 + l*C_);
  }

  unpool_x<<<N0*32/256, 256, 0, stream>>>(x, x1, perm);
  unpool_e<<<E1C*32/256, 256, 0, stream>>>(e, e1, pe);

  for (int l = 4; l < 6; ++l) {
    mlp_kernel<0><<<E0/64, 256, 0, stream>>>(e, x, srcF, dstF,
        We1 + l*384*C_, be1 + l*C_, We2 + l*C_*C_, be2 + l*C_);
    agg_fine<<<N0*32/256, 256, 0, stream>>>(e, agg);
    mlp_kernel<1><<<N0/64, 256, 0, stream>>>(x, agg, nullptr, nullptr,
        Wn1 + l*256*C_, bn1 + l*C_, Wn2 + l*C_*C_, bn2 + l*C_);
  }
}

// Round 5
// 475.294 us; speedup vs baseline: 2.1500x; 2.1500x over previous
//
#include <hip/hip_runtime.h>

#define C_ 128
#define N0 16384
#define E0 65024
#define NC_ 1024
#define E1C 3968
#define LSTR 40   // LDS row stride in shorts (32 k + 8 pad) = 80B: 16B-aligned, 2-way banks (free)

typedef __attribute__((ext_vector_type(8))) short bf16x8;
typedef __attribute__((ext_vector_type(4))) float f32x4;

// weight table offsets (in shorts) inside the ws bf16 region
#define OFF_WE1 0
#define OFF_WE2 294912
#define OFF_WN1 393216
#define OFF_WN2 589824
#define W_TOTAL 688128

__device__ __forceinline__ void bsplit(float a, unsigned short& hi, unsigned short& lo) {
  unsigned ab = __float_as_uint(a);
  unsigned hb = ab & 0xFFFF0000u;          // truncate to bf16
  hi = (unsigned short)(hb >> 16);
  float r = a - __uint_as_float(hb);       // exact (Sterbenz)
  lo = (unsigned short)(__float_as_uint(r) >> 16);  // truncate residual
}

__device__ __forceinline__ int cprefix(int ci, int cj) {
  int rows = (ci == 0) ? 0 : (94 + (ci - 1) * 126);
  int v = (ci > 0) + (ci < 31);
  int within = (cj == 0) ? 0 : (2 * cj - 1);
  return rows + within + cj * v;
}

__device__ __forceinline__ void add4(float4& s, const float* p) {
  float4 v = *(const float4*)p;
  s.x += v.x; s.y += v.y; s.z += v.z; s.w += v.w;
}

// ---- one-time (per launch) weight transpose + bf16 hi/lo split ----
// dst layout per tensor: [layer][K/32 chunks][128 cols][32 k] shorts
__global__ void prep_weights(const float* __restrict__ We1, const float* __restrict__ We2,
                             const float* __restrict__ Wn1, const float* __restrict__ Wn2,
                             short* __restrict__ wh, short* __restrict__ wl) {
  int idx = blockIdx.x * 256 + threadIdx.x;   // < 688128
  const float* src; int Kt, off, rem;
  if (idx < 294912)      { src = We1; Kt = 384; off = OFF_WE1; rem = idx; }
  else if (idx < 393216) { src = We2; Kt = 128; off = OFF_WE2; rem = idx - 294912; }
  else if (idx < 589824) { src = Wn1; Kt = 256; off = OFF_WN1; rem = idx - 393216; }
  else                   { src = Wn2; Kt = 128; off = OFF_WN2; rem = idx - 589824; }
  int per_layer = Kt << 7;           // Kt*128
  int layer = rem / per_layer;
  int r2 = rem - layer * per_layer;
  int k = r2 >> 7;
  int col = r2 & 127;
  float a = src[layer * per_layer + (k << 7) + col];
  unsigned short hi, lo;
  bsplit(a, hi, lo);
  int dst = off + layer * ((Kt >> 5) << 12) + ((k >> 5) << 12) + (col << 5) + (k & 31);
  wh[dst] = (short)hi;
  wl[dst] = (short)lo;
}

// MODE 0: edge MLP, K1=384, A = [e_row | x[src] | x[dst]]
// MODE 1: node MLP, K1=256, A = [x_row | agg_row]
// io = io + relu(A@W1 + b1)@W2 + b2, via bf16 hi/lo split MFMA (3 mfma per product)
template<int MODE>
__global__ __launch_bounds__(256, 2) void mlp_mfma(
    float* __restrict__ io, const float* __restrict__ xin,
    const int* __restrict__ srcI, const int* __restrict__ dstI,
    const short* __restrict__ W1h, const short* __restrict__ W1l,
    const float* __restrict__ b1,
    const short* __restrict__ W2h, const short* __restrict__ W2l,
    const float* __restrict__ b2)
{
  __shared__ alignas(16) short sAh[64 * LSTR], sAl[64 * LSTR];
  __shared__ alignas(16) short sWh[128 * LSTR], sWl[128 * LSTR];
  __shared__ int sS[64], sD[64];

  const int tid = threadIdx.x;
  const int r0 = blockIdx.x * 64;
  const int w   = tid >> 6;     // wave 0..3 -> rows [w*16, w*16+16)
  const int l   = tid & 63;
  const int c15 = l & 15;
  const int kg  = l >> 4;       // k-group 0..3

  if (MODE == 0) {
    if (tid < 64) sS[tid] = srcI[r0 + tid];
    else if (tid < 128) sD[tid - 64] = dstI[r0 + tid - 64];
    __syncthreads();
  }

  f32x4 acc[8];
  #pragma unroll
  for (int t = 0; t < 8; ++t) acc[t] = (f32x4){0.f, 0.f, 0.f, 0.f};

  const int NKT = (MODE == 0) ? 12 : 8;
  for (int kt = 0; kt < NKT; ++kt) {
    const int region = kt >> 2;
    const int colbase = (kt & 3) * 32;
    // --- stage A tile (64 rows x 32 k) as bf16 hi/lo ---
    #pragma unroll
    for (int tt = 0; tt < 2; ++tt) {
      int s = tid * 2 + tt;            // 0..511 float4 slots
      int row = s >> 3, q = s & 7;     // q: float4 index within 32-k row
      const float* rp;
      if (MODE == 0) {
        rp = (region == 0) ? io + (r0 + row) * C_
           : (region == 1) ? xin + sS[row] * C_
                           : xin + sD[row] * C_;
      } else {
        rp = (region == 0) ? io + (r0 + row) * C_ : xin + (r0 + row) * C_;
      }
      float4 a = *(const float4*)(rp + colbase + q * 4);
      unsigned short h0,h1,h2,h3, q0,q1,q2,q3;
      bsplit(a.x, h0, q0); bsplit(a.y, h1, q1);
      bsplit(a.z, h2, q2); bsplit(a.w, h3, q3);
      *(uint2*)&sAh[row * LSTR + q * 4] =
          make_uint2((unsigned)h0 | ((unsigned)h1 << 16), (unsigned)h2 | ((unsigned)h3 << 16));
      *(uint2*)&sAl[row * LSTR + q * 4] =
          make_uint2((unsigned)q0 | ((unsigned)q1 << 16), (unsigned)q2 | ((unsigned)q3 << 16));
    }
    // --- stage W1 chunk kt: [128 cols][32 k] hi/lo (pre-chunked, coalesced) ---
    {
      const short* srcH = W1h + (kt << 12);
      const short* srcL = W1l + (kt << 12);
      #pragma unroll
      for (int u0 = 0; u0 < 2; ++u0) {
        int u = tid + u0 * 256;        // 0..511 16B units
        int col = u >> 2, part = u & 3;
        *(uint4*)&sWh[col * LSTR + part * 8] = *(const uint4*)(srcH + u * 8);
        *(uint4*)&sWl[col * LSTR + part * 8] = *(const uint4*)(srcL + u * 8);
      }
    }
    __syncthreads();
    // --- MFMA: 8 col-tiles x 3 split terms ---
    bf16x8 ah = *(const bf16x8*)&sAh[(w * 16 + c15) * LSTR + kg * 8];
    bf16x8 al = *(const bf16x8*)&sAl[(w * 16 + c15) * LSTR + kg * 8];
    #pragma unroll
    for (int t = 0; t < 8; ++t) {
      bf16x8 wh = *(const bf16x8*)&sWh[(t * 16 + c15) * LSTR + kg * 8];
      bf16x8 wl = *(const bf16x8*)&sWl[(t * 16 + c15) * LSTR + kg * 8];
      acc[t] = __builtin_amdgcn_mfma_f32_16x16x32_bf16(ah, wh, acc[t], 0, 0, 0);
      acc[t] = __builtin_amdgcn_mfma_f32_16x16x32_bf16(ah, wl, acc[t], 0, 0, 0);
      acc[t] = __builtin_amdgcn_mfma_f32_16x16x32_bf16(al, wh, acc[t], 0, 0, 0);
    }
    __syncthreads();
  }

  // bias1 (thread's col for tile t is t*16+c15)
  float b1v[8];
  #pragma unroll
  for (int t = 0; t < 8; ++t) b1v[t] = b1[t * 16 + c15];

  f32x4 acc2[8];
  #pragma unroll
  for (int t = 0; t < 8; ++t) acc2[t] = (f32x4){0.f, 0.f, 0.f, 0.f};

  // GEMM2: H(64x128) @ W2(128x128), K in 4 chunks of 32; H restaged via LDS
  #pragma unroll
  for (int kc = 0; kc < 4; ++kc) {
    __syncthreads();   // previous reads of sA/sW done
    // write H chunk cols [kc*32, kc*32+32): tiles 2kc, 2kc+1 (wave-local rows)
    #pragma unroll
    for (int tt = 0; tt < 2; ++tt) {
      const int t = kc * 2 + tt;
      #pragma unroll
      for (int r = 0; r < 4; ++r) {
        float h = fmaxf(acc[t][r] + b1v[t], 0.f);
        unsigned short hh, hl;
        bsplit(h, hh, hl);
        int row = w * 16 + kg * 4 + r;
        int k = tt * 16 + c15;
        sAh[row * LSTR + k] = (short)hh;
        sAl[row * LSTR + k] = (short)hl;
      }
    }
    // stage W2 chunk kc
    {
      const short* srcH = W2h + (kc << 12);
      const short* srcL = W2l + (kc << 12);
      #pragma unroll
      for (int u0 = 0; u0 < 2; ++u0) {
        int u = tid + u0 * 256;
        int col = u >> 2, part = u & 3;
        *(uint4*)&sWh[col * LSTR + part * 8] = *(const uint4*)(srcH + u * 8);
        *(uint4*)&sWl[col * LSTR + part * 8] = *(const uint4*)(srcL + u * 8);
      }
    }
    __syncthreads();
    bf16x8 ah = *(const bf16x8*)&sAh[(w * 16 + c15) * LSTR + kg * 8];
    bf16x8 al = *(const bf16x8*)&sAl[(w * 16 + c15) * LSTR + kg * 8];
    #pragma unroll
    for (int t = 0; t < 8; ++t) {
      bf16x8 wh = *(const bf16x8*)&sWh[(t * 16 + c15) * LSTR + kg * 8];
      bf16x8 wl = *(const bf16x8*)&sWl[(t * 16 + c15) * LSTR + kg * 8];
      acc2[t] = __builtin_amdgcn_mfma_f32_16x16x32_bf16(ah, wh, acc2[t], 0, 0, 0);
      acc2[t] = __builtin_amdgcn_mfma_f32_16x16x32_bf16(ah, wl, acc2[t], 0, 0, 0);
      acc2[t] = __builtin_amdgcn_mfma_f32_16x16x32_bf16(al, wh, acc2[t], 0, 0, 0);
    }
  }

  // epilogue: io += acc2 + b2   (C frag: row = kg*4+r, col = t*16+c15)
  #pragma unroll
  for (int t = 0; t < 8; ++t) {
    float b2v = b2[t * 16 + c15];
    #pragma unroll
    for (int r = 0; r < 4; ++r) {
      int row = r0 + w * 16 + kg * 4 + r;
      float* p = io + row * C_ + t * 16 + c15;
      *p += acc2[t][r] + b2v;
    }
  }
}

// ---- structural kernels (fp32, unchanged) ----
__global__ void agg_fine(const float* __restrict__ e, float* __restrict__ agg) {
  int idx = blockIdx.x * 256 + threadIdx.x;
  int n = idx >> 5;
  int c4 = (idx & 31) * 4;
  int i = n >> 7, j = n & 127;
  float4 s = make_float4(0.f, 0.f, 0.f, 0.f);
  if (j >= 1)   add4(s, e + (i*127 + (j-1)) * C_ + c4);
  if (j <= 126) add4(s, e + (16256 + i*127 + j) * C_ + c4);
  if (i >= 1)   add4(s, e + (32512 + (i-1)*128 + j) * C_ + c4);
  if (i <= 126) add4(s, e + (48768 + i*128 + j) * C_ + c4);
  *(float4*)(agg + n * C_ + c4) = s;
}

__global__ void agg_coarse(const float* __restrict__ e1, float* __restrict__ agg1) {
  int idx = blockIdx.x * 256 + threadIdx.x;
  int m = idx >> 5;
  int c4 = (idx & 31) * 4;
  int ci = m >> 5, cj = m & 31;
  float4 s = make_float4(0.f, 0.f, 0.f, 0.f);
  if (ci > 0)  add4(s, e1 + (cprefix(ci-1,cj) + (ci-1>0) + (cj>0) + (cj<31)) * C_ + c4);
  if (cj > 0)  add4(s, e1 + (cprefix(ci,cj-1) + (ci>0) + (cj-1>0)) * C_ + c4);
  if (cj < 31) add4(s, e1 + (cprefix(ci,cj+1) + (ci>0)) * C_ + c4);
  if (ci < 31) add4(s, e1 + (cprefix(ci+1,cj)) * C_ + c4);
  *(float4*)(agg1 + m * C_ + c4) = s;
}

__global__ void pool_x(const float* __restrict__ x, float* __restrict__ x1) {
  int idx = blockIdx.x * 256 + threadIdx.x;
  int m = idx >> 5;
  int c4 = (idx & 31) * 4;
  int ci = m >> 5, cj = m & 31;
  float4 s = make_float4(0.f, 0.f, 0.f, 0.f);
  #pragma unroll
  for (int a = 0; a < 4; ++a)
    #pragma unroll
    for (int b = 0; b < 4; ++b)
      add4(s, x + ((4*ci + a) * 128 + 4*cj + b) * C_ + c4);
  s.x *= 0.0625f; s.y *= 0.0625f; s.z *= 0.0625f; s.w *= 0.0625f;
  *(float4*)(x1 + m * C_ + c4) = s;
}

__global__ void pool_e(const float* __restrict__ e, float* __restrict__ e1) {
  int idx = blockIdx.x * 256 + threadIdx.x;
  int combo = idx >> 5;
  int c4 = (idx & 31) * 4;
  int m = combo >> 2, dir = combo & 3;
  int ci = m >> 5, cj = m & 31;
  int cid, f0, fstep;
  if (dir == 0) { if (ci == 0) return;
    cid = cprefix(ci,cj);
    f0 = 48768 + (4*ci - 1) * 128 + 4*cj; fstep = 1;
  } else if (dir == 1) { if (cj == 0) return;
    cid = cprefix(ci,cj) + (ci>0);
    f0 = 16256 + (4*ci) * 127 + 4*cj - 1; fstep = 127;
  } else if (dir == 2) { if (cj == 31) return;
    cid = cprefix(ci,cj) + (ci>0) + (cj>0);
    f0 = (4*ci) * 127 + 4*cj + 3; fstep = 127;
  } else { if (ci == 31) return;
    cid = cprefix(ci,cj) + (ci>0) + (cj>0) + (cj<31);
    f0 = 32512 + (4*ci + 3) * 128 + 4*cj; fstep = 1;
  }
  float4 s = make_float4(0.f, 0.f, 0.f, 0.f);
  #pragma unroll
  for (int k = 0; k < 4; ++k)
    add4(s, e + (f0 + k * fstep) * C_ + c4);
  *(float4*)(e1 + cid * C_ + c4) = s;
}

__global__ void unpool_x(float* __restrict__ x, const float* __restrict__ x1,
                         const int* __restrict__ perm) {
  int idx = blockIdx.x * 256 + threadIdx.x;
  int n = idx >> 5, c4 = (idx & 31) * 4;
  int m = perm[n];
  float4 v = *(const float4*)(x + n * C_ + c4);
  add4(v, x1 + m * C_ + c4);
  *(float4*)(x + n * C_ + c4) = v;
}

__global__ void unpool_e(float* __restrict__ e, const float* __restrict__ e1,
                         const int* __restrict__ pe) {
  int idx = blockIdx.x * 256 + threadIdx.x;
  int k = idx >> 5, c4 = (idx & 31) * 4;
  int fe = pe[k];
  float4 v = *(const float4*)(e + fe * C_ + c4);
  add4(v, e1 + k * C_ + c4);
  *(float4*)(e + fe * C_ + c4) = v;
}

extern "C" void kernel_launch(void* const* d_in, const int* in_sizes, int n_in,
                              void* d_out, int out_size, void* d_ws, size_t ws_size,
                              hipStream_t stream) {
  const float* in_x  = (const float*)d_in[0];
  const float* in_ea = (const float*)d_in[1];
  const float* We1 = (const float*)d_in[2];
  const float* be1 = (const float*)d_in[3];
  const float* We2 = (const float*)d_in[4];
  const float* be2 = (const float*)d_in[5];
  const float* Wn1 = (const float*)d_in[6];
  const float* bn1 = (const float*)d_in[7];
  const float* Wn2 = (const float*)d_in[8];
  const float* bn2 = (const float*)d_in[9];
  const int* ei   = (const int*)d_in[10];
  const int* perm = (const int*)d_in[11];
  const int* pei  = (const int*)d_in[12];
  const int* pe   = (const int*)d_in[14];

  // outputs live in place
  float* x = (float*)d_out;             // N0 x 128
  float* e = x + (size_t)N0 * C_;       // E0 x 128
  // scratch in d_ws: fp32 buffers then bf16 weight tables
  float* agg  = (float*)d_ws;           // N0 x 128
  float* x1   = agg + (size_t)N0 * C_;  // NC x 128
  float* e1   = x1 + (size_t)NC_ * C_;  // E1 x 128
  float* agg1 = e1 + (size_t)E1C * C_;  // NC x 128
  short* wsH  = (short*)(agg1 + (size_t)NC_ * C_);   // 688128 shorts (16B-aligned)
  short* wsL  = wsH + W_TOTAL;

  hipMemcpyAsync(x, in_x, (size_t)N0 * C_ * 4, hipMemcpyDeviceToDevice, stream);
  hipMemcpyAsync(e, in_ea, (size_t)E0 * C_ * 4, hipMemcpyDeviceToDevice, stream);

  prep_weights<<<W_TOTAL / 256, 256, 0, stream>>>(We1, We2, Wn1, Wn2, wsH, wsL);

  const int* srcF = ei;  const int* dstF = ei + E0;
  const int* srcC = pei; const int* dstC = pei + E1C;

  // per-layer weight table offsets (shorts)
  #define WE1_OFF(l) (OFF_WE1 + (l) * 49152)
  #define WE2_OFF(l) (OFF_WE2 + (l) * 16384)
  #define WN1_OFF(l) (OFF_WN1 + (l) * 32768)
  #define WN2_OFF(l) (OFF_WN2 + (l) * 16384)

  for (int l = 0; l < 2; ++l) {
    mlp_mfma<0><<<E0/64, 256, 0, stream>>>(e, x, srcF, dstF,
        wsH + WE1_OFF(l), wsL + WE1_OFF(l), be1 + l*C_,
        wsH + WE2_OFF(l), wsL + WE2_OFF(l), be2 + l*C_);
    agg_fine<<<N0*32/256, 256, 0, stream>>>(e, agg);
    mlp_mfma<1><<<N0/64, 256, 0, stream>>>(x, agg, nullptr, nullptr,
        wsH + WN1_OFF(l), wsL + WN1_OFF(l), bn1 + l*C_,
        wsH + WN2_OFF(l), wsL + WN2_OFF(l), bn2 + l*C_);
  }

  pool_x<<<NC_*32/256, 256, 0, stream>>>(x, x1);
  pool_e<<<NC_*4*32/256, 256, 0, stream>>>(e, e1);

  for (int l = 2; l < 4; ++l) {
    mlp_mfma<0><<<E1C/64, 256, 0, stream>>>(e1, x1, srcC, dstC,
        wsH + WE1_OFF(l), wsL + WE1_OFF(l), be1 + l*C_,
        wsH + WE2_OFF(l), wsL + WE2_OFF(l), be2 + l*C_);
    agg_coarse<<<NC_*32/256, 256, 0, stream>>>(e1, agg1);
    mlp_mfma<1><<<NC_/64, 256, 0, stream>>>(x1, agg1, nullptr, nullptr,
        wsH + WN1_OFF(l), wsL + WN1_OFF(l), bn1 + l*C_,
        wsH + WN2_OFF(l), wsL + WN2_OFF(l), bn2 + l*C_);
  }

  unpool_x<<<N0*32/256, 256, 0, stream>>>(x, x1, perm);
  unpool_e<<<E1C*32/256, 256, 0, stream>>>(e, e1, pe);

  for (int l = 4; l < 6; ++l) {
    mlp_mfma<0><<<E0/64, 256, 0, stream>>>(e, x, srcF, dstF,
        wsH + WE1_OFF(l), wsL + WE1_OFF(l), be1 + l*C_,
        wsH + WE2_OFF(l), wsL + WE2_OFF(l), be2 + l*C_);
    agg_fine<<<N0*32/256, 256, 0, stream>>>(e, agg);
    mlp_mfma<1><<<N0/64, 256, 0, stream>>>(x, agg, nullptr, nullptr,
        wsH + WN1_OFF(l), wsL + WN1_OFF(l), bn1 + l*C_,
        wsH + WN2_OFF(l), wsL + WN2_OFF(l), bn2 + l*C_);
  }
}